// Round 8
// baseline (206.884 us; speedup 1.0000x reference)
//
#include <hip/hip_runtime.h>
#include <hip/hip_bf16.h>
#include <math.h>

#define C_IN  64
#define HID   128
#define C_OUT 64
#define K1_NODES 64
#define EA_G  3072

typedef __attribute__((ext_vector_type(8))) short s16x8;   // 8 bf16 (4 VGPR)
typedef __attribute__((ext_vector_type(4))) float f32x4;   // MFMA acc
typedef __attribute__((ext_vector_type(2))) float f32x2;   // packed-fp32 pair

// ---------------------------------------------------------------------------
// Fast GELU (tanh form), PACKED 2-wide. Bit-identical math to prior rounds.
// ---------------------------------------------------------------------------
__device__ __forceinline__ f32x2 gelu2(f32x2 x) {
    f32x2 t  = x * x;                                   // pk_mul
    f32x2 p  = t * 0.10294455f + 2.30211462f;           // pk_fma
    f32x2 xp = x * p;                                   // pk_mul
    f32x2 E;
    E.x = __builtin_amdgcn_exp2f(xp.x);                 // trans
    E.y = __builtin_amdgcn_exp2f(xp.y);                 // trans
    f32x2 Ep = E + 1.0f;                                // pk_add
    f32x2 r;
    r.x = __builtin_amdgcn_rcpf(Ep.x);                  // trans
    r.y = __builtin_amdgcn_rcpf(Ep.y);                  // trans
    return x - x * r;                                   // pk_fma
}

__device__ __forceinline__ float4 fma4(float s, float4 w, float4 acc) {
    acc.x = fmaf(s, w.x, acc.x); acc.y = fmaf(s, w.y, acc.y);
    acc.z = fmaf(s, w.z, acc.z); acc.w = fmaf(s, w.w, acc.w);
    return acc;
}

__device__ __forceinline__ unsigned pk_bf16(float lo, float hi) {
    union { __hip_bfloat162 v; unsigned u; } cv;
    cv.v = __float22bfloat162_rn(make_float2(lo, hi));
    return cv.u;
}

// ---------------------------------------------------------------------------
// Kernel 1: per-node SELF half of the first linear + table prep.
//   B[n][h]  = X[n][:] . W1[64:128,h] + b1      (f32, streamed per row)
//   Xg[n][c] = bf16(X[n][c])                    (6.4 MB gather table)
// Block 0: W2T[c][k] bf16 (for K3) and W1TT[h][k] bf16 (k-major frags of
// W1[0:64,:], the per-edge MFMA B-operand). Also builds bsplit.
// ---------------------------------------------------------------------------
__global__ __launch_bounds__(512, 2) void precompute_b(
    const float* __restrict__ X, const float* __restrict__ W1,
    const float* __restrict__ b1, const float* __restrict__ W2,
    const int* __restrict__ rs,
    unsigned* __restrict__ Xg, float* __restrict__ B,
    unsigned short* __restrict__ W2T, unsigned short* __restrict__ W1TT,
    int* __restrict__ bsplit, int N, int E, int G)
{
    __shared__ float W1s[C_IN * HID];         // bottom half [64][128] = 32 KiB
    __shared__ float xs[K1_NODES * C_IN];     // 16 KiB
    int tid = threadIdx.x;

    for (int i = tid; i < (C_IN * HID) / 4; i += 512)
        ((float4*)W1s)[i] = ((const float4*)(W1 + C_IN * HID))[i];

    int base = blockIdx.x * K1_NODES;
    int nLoc = min(K1_NODES, N - base);
    for (int i = tid; i < nLoc * (C_IN / 4); i += 512)
        ((float4*)xs)[i] = ((const float4*)(X + (size_t)base * C_IN))[i];

    if (blockIdx.x == 0) {                     // one-time weight repacks
        for (int i = tid; i < C_OUT * HID; i += 512) {
            int c = i >> 7, k = i & (HID - 1);
            W2T[i] = (unsigned short)pk_bf16(W2[k * C_OUT + c], 0.f);
        }
        for (int i = tid; i < HID * C_IN; i += 512) {   // W1TT[h][k]=W1[k][h]
            int h = i >> 6, k = i & (C_IN - 1);
            W1TT[i] = (unsigned short)pk_bf16(W1[k * HID + h], 0.f);
        }
    }

    {   // block->row partition for edge_mlp (lane-parallel binary search)
        int gi = blockIdx.x * 512 + tid;
        if (gi <= G) {
            int t = (int)(((long long)E * gi) / G);
            int lo = 0, hi = N;
            while (lo < hi) { int mm = (lo + hi) >> 1; if (rs[mm] < t) lo = mm + 1; else hi = mm; }
            bsplit[gi] = lo;
        }
    }

    __syncthreads();

    // Xg: bf16 conversion of this block's nodes (uses all 512 threads)
    for (int i = tid; i < nLoc * (C_IN / 2); i += 512) {
        int n = i >> 5, d2 = i & 31;
        Xg[(size_t)(base + n) * (C_IN / 2) + d2] =
            pk_bf16(xs[n * C_IN + 2 * d2], xs[n * C_IN + 2 * d2 + 1]);
    }

    int quad = (tid & 31) * 4;    // h-quad 0,4,...,124
    int slot = tid >> 5;          // 0..15, owns nodes 4*slot .. 4*slot+3
    int s0   = slot * 4;
    if (s0 >= nLoc) return;

    float4 b0 = {}, b1r = {}, b2r = {}, b3 = {};

    const float* xr0 = xs + (s0 + 0) * C_IN;
    const float* xr1 = xs + (s0 + 1) * C_IN;
    const float* xr2 = xs + (s0 + 2) * C_IN;
    const float* xr3 = xs + (s0 + 3) * C_IN;

#define K1STEP(c, CMP)                                                      \
    do {                                                                    \
        float4 wb = *(const float4*)&W1s[(c) * HID + quad];                 \
        b0  = fma4(xv0.CMP, wb, b0);  b1r = fma4(xv1.CMP, wb, b1r);         \
        b2r = fma4(xv2.CMP, wb, b2r); b3  = fma4(xv3.CMP, wb, b3);          \
    } while (0)

#pragma unroll 1
    for (int c4 = 0; c4 < C_IN; c4 += 4) {
        float4 xv0 = *(const float4*)&xr0[c4];
        float4 xv1 = *(const float4*)&xr1[c4];
        float4 xv2 = *(const float4*)&xr2[c4];
        float4 xv3 = *(const float4*)&xr3[c4];
        K1STEP(c4 + 0, x);
        K1STEP(c4 + 1, y);
        K1STEP(c4 + 2, z);
        K1STEP(c4 + 3, w);
    }
#undef K1STEP

    float4 bb = *(const float4*)(b1 + quad);
    b0.x += bb.x;  b0.y += bb.y;  b0.z += bb.z;  b0.w += bb.w;
    b1r.x += bb.x; b1r.y += bb.y; b1r.z += bb.z; b1r.w += bb.w;
    b2r.x += bb.x; b2r.y += bb.y; b2r.z += bb.z; b2r.w += bb.w;
    b3.x += bb.x;  b3.y += bb.y;  b3.z += bb.z;  b3.w += bb.w;

    size_t boff = (size_t)(base + s0) * HID + quad;
    if (s0 + 0 < nLoc) *(float4*)(B + boff)           = b0;
    if (s0 + 1 < nLoc) *(float4*)(B + boff + HID)     = b1r;
    if (s0 + 2 < nLoc) *(float4*)(B + boff + 2 * HID) = b2r;
    if (s0 + 3 < nLoc) *(float4*)(B + boff + 3 * HID) = b3;
}

// ---------------------------------------------------------------------------
// Kernel 2: edge MLP via MFMA over gathered X rows.
//   Per 16-edge row-aligned tile: gather 16 X rows (2 dwordx4/lane from the
//   6.4 MB bf16 table -> HALF the fetch of the old 12.8 MB A16 table),
//   P[16][128] = Xg_tile @ W1_top via 16x mfma_16x16x32_bf16 (layout mirrors
//   the proven h_w2_mfma fragment pattern), add row's self-term B, GELU
//   (same gelu2), masked sum across edges, mean, bf16 Hout row.
//   1-tile-ahead gather prefetch; W1 fragments hoisted in registers.
// ---------------------------------------------------------------------------
__global__ __launch_bounds__(256, 1) void edge_mlp(
    const unsigned short* __restrict__ Xg, const float* __restrict__ B,
    const int* __restrict__ nbr, const int* __restrict__ rs,
    const int* __restrict__ bsplit, unsigned short* __restrict__ Hout,
    const unsigned short* __restrict__ W1TT, int N, int E, int G)
{
    int wave = threadIdx.x >> 6, lane = threadIdx.x & 63;
    int l15 = lane & 15, kg = lane >> 4;
    int b = blockIdx.x;

    int r0 = bsplit[b];
    int r1 = (b == G - 1) ? N : bsplit[b + 1];
    if (r0 + wave >= r1) return;

    // hoist W1 fragments: w1f[nt][ks] = W1TT[(nt*16+l15)][ks*32 + kg*8 ..+8]
    s16x8 w1f[8][2];
#pragma unroll
    for (int nt = 0; nt < 8; ++nt)
#pragma unroll
        for (int ks = 0; ks < 2; ++ks)
            w1f[nt][ks] = *(const s16x8*)(W1TT + (nt * 16 + l15) * C_IN + ks * 32 + kg * 8);

    for (int row = r0 + wave; row < r1; row += 4) {
        int s = rs[row], e = rs[row + 1], cnt = e - s;

        float bv[8];
        const float* bp = B + (size_t)row * HID + l15;
#pragma unroll
        for (int nt = 0; nt < 8; ++nt) bv[nt] = bp[nt * 16];

        f32x2 hs[8];
#pragma unroll
        for (int nt = 0; nt < 8; ++nt) { hs[nt].x = 0.f; hs[nt].y = 0.f; }

        if (cnt > 0) {
            int tb = s;
            int o0 = min(l15, e - 1 - tb);
            int idx0 = nbr[tb + o0];
            const unsigned short* xp0 = Xg + ((size_t)(unsigned)idx0 << 6) + kg * 8;
            s16x8 ga0 = *(const s16x8*)xp0;
            s16x8 gb0 = *(const s16x8*)(xp0 + 32);

            for (;;) {
                int tn = tb + 16;
                s16x8 ga1 = ga0, gb1 = gb0;
                if (tn < e) {                      // prefetch next tile's gather
                    int o1 = min(l15, e - 1 - tn);
                    int idx1 = nbr[tn + o1];
                    const unsigned short* xp1 = Xg + ((size_t)(unsigned)idx1 << 6) + kg * 8;
                    ga1 = *(const s16x8*)xp1;
                    gb1 = *(const s16x8*)(xp1 + 32);
                }

                // P = Xg_tile @ W1_top  (K=64 as two K=32 steps)
                f32x4 p[8];
#pragma unroll
                for (int nt = 0; nt < 8; ++nt) {
                    f32x4 z = {0.f, 0.f, 0.f, 0.f};
                    p[nt] = __builtin_amdgcn_mfma_f32_16x16x32_bf16(ga0, w1f[nt][0], z, 0, 0, 0);
                    p[nt] = __builtin_amdgcn_mfma_f32_16x16x32_bf16(gb0, w1f[nt][1], p[nt], 0, 0, 0);
                }

                int rem = e - tb;
                if (rem >= 16) {                   // full tile (wave-uniform)
#pragma unroll
                    for (int nt = 0; nt < 8; ++nt) {
                        f32x2 vlo, vhi;
                        vlo.x = p[nt][0] + bv[nt]; vlo.y = p[nt][1] + bv[nt];
                        vhi.x = p[nt][2] + bv[nt]; vhi.y = p[nt][3] + bv[nt];
                        hs[nt] += gelu2(vlo);
                        hs[nt] += gelu2(vhi);
                    }
                } else {                           // masked tail tile
                    int me = kg * 4;
                    f32x2 ml, mh;
                    ml.x = (me + 0 < rem) ? 1.f : 0.f;
                    ml.y = (me + 1 < rem) ? 1.f : 0.f;
                    mh.x = (me + 2 < rem) ? 1.f : 0.f;
                    mh.y = (me + 3 < rem) ? 1.f : 0.f;
#pragma unroll
                    for (int nt = 0; nt < 8; ++nt) {
                        f32x2 vlo, vhi;
                        vlo.x = p[nt][0] + bv[nt]; vlo.y = p[nt][1] + bv[nt];
                        vhi.x = p[nt][2] + bv[nt]; vhi.y = p[nt][3] + bv[nt];
                        hs[nt] += gelu2(vlo) * ml;
                        hs[nt] += gelu2(vhi) * mh;
                    }
                }

                if (tn >= e) break;
                tb = tn; ga0 = ga1; gb0 = gb1;
            }
        }

        // reduce across the 4 kg groups; mean; bf16 store (group 0 writes)
        float sc = (cnt > 0) ? 1.f / (float)cnt : 0.f;
#pragma unroll
        for (int nt = 0; nt < 8; ++nt) {
            float h = hs[nt].x + hs[nt].y;
            h += __shfl_xor(h, 16);
            h += __shfl_xor(h, 32);
            if (kg == 0)
                Hout[(size_t)row * HID + nt * 16 + l15] =
                    (unsigned short)(pk_bf16(h * sc, 0.f) & 0xffffu);
        }
    }
}

// ---------------------------------------------------------------------------
// Kernel 3: out = Hbar @ W2 + b2 via MFMA (bf16 in, f32 out). Unchanged.
// ---------------------------------------------------------------------------
__global__ __launch_bounds__(256) void h_w2_mfma(
    const unsigned short* __restrict__ H, const unsigned short* __restrict__ W2T,
    const float* __restrict__ b2, const int* __restrict__ rs,
    float* __restrict__ out, int N)
{
    int wave = threadIdx.x >> 6, lane = threadIdx.x & 63;
    int base = (blockIdx.x * 4 + wave) * 16;
    if (base >= N) return;

    int r16 = lane & 15;
    int kg  = lane >> 4;

    const unsigned short* hrow = H + (size_t)(base + r16) * HID + kg * 8;
    const unsigned short* wc0  = W2T + (size_t)(0 * 16 + r16) * HID + kg * 8;
    const unsigned short* wc1  = W2T + (size_t)(1 * 16 + r16) * HID + kg * 8;
    const unsigned short* wc2  = W2T + (size_t)(2 * 16 + r16) * HID + kg * 8;
    const unsigned short* wc3  = W2T + (size_t)(3 * 16 + r16) * HID + kg * 8;

    f32x4 acc0 = {0.f, 0.f, 0.f, 0.f};
    f32x4 acc1 = acc0, acc2 = acc0, acc3 = acc0;

#pragma unroll
    for (int kk = 0; kk < 4; ++kk) {
        s16x8 a  = *(const s16x8*)(hrow + kk * 32);
        s16x8 f0 = *(const s16x8*)(wc0 + kk * 32);
        s16x8 f1 = *(const s16x8*)(wc1 + kk * 32);
        s16x8 f2 = *(const s16x8*)(wc2 + kk * 32);
        s16x8 f3 = *(const s16x8*)(wc3 + kk * 32);
        acc0 = __builtin_amdgcn_mfma_f32_16x16x32_bf16(a, f0, acc0, 0, 0, 0);
        acc1 = __builtin_amdgcn_mfma_f32_16x16x32_bf16(a, f1, acc1, 0, 0, 0);
        acc2 = __builtin_amdgcn_mfma_f32_16x16x32_bf16(a, f2, acc2, 0, 0, 0);
        acc3 = __builtin_amdgcn_mfma_f32_16x16x32_bf16(a, f3, acc3, 0, 0, 0);
    }

    float bia0 = b2[r16], bia1 = b2[16 + r16], bia2 = b2[32 + r16], bia3 = b2[48 + r16];

#pragma unroll
    for (int r = 0; r < 4; ++r) {
        int rowi = base + kg * 4 + r;
        if (rowi < N) {
            float mmk = (rs[rowi + 1] > rs[rowi]) ? 1.f : 0.f;
            float* o = out + (size_t)rowi * C_OUT;
            o[r16]      = mmk * (acc0[r] + bia0);
            o[16 + r16] = mmk * (acc1[r] + bia1);
            o[32 + r16] = mmk * (acc2[r] + bia2);
            o[48 + r16] = mmk * (acc3[r] + bia3);
        }
    }
}

// ---------------------------------------------------------------------------
extern "C" void kernel_launch(void* const* d_in, const int* in_sizes, int n_in,
                              void* d_out, int out_size, void* d_ws, size_t ws_size,
                              hipStream_t stream) {
    const float* X  = (const float*)d_in[0];
    const float* W1 = (const float*)d_in[1];
    const float* b1 = (const float*)d_in[2];
    const float* W2 = (const float*)d_in[3];
    const float* b2 = (const float*)d_in[4];
    const int*   nbr = (const int*)d_in[5];
    const int*   rs  = (const int*)d_in[6];
    float* outp = (float*)d_out;

    int N = in_sizes[6] - 1;                  // row_splits has N+1 entries
    int E = in_sizes[5];                      // total edges

    int G = EA_G;

    // workspace layout (~45 MB):
    unsigned*       Xg   = (unsigned*)d_ws;                          // N*32 dw (6.4 MB)
    float*          Bbuf = (float*)(Xg + (size_t)N * (C_IN / 2));    // N*128 f32
    unsigned*       Hout = (unsigned*)(Bbuf + (size_t)N * HID);      // N*64 dw
    unsigned short* W2T  = (unsigned short*)(Hout + (size_t)N * (HID / 2)); // 8192
    unsigned short* W1TT = W2T + C_OUT * HID;                        // 8192
    int*            bsplit = (int*)(W1TT + HID * C_IN);              // G+1 ints

    int g1 = (N + K1_NODES - 1) / K1_NODES;
    hipLaunchKernelGGL(precompute_b, dim3(g1), dim3(512), 0, stream,
                       X, W1, b1, W2, rs, Xg, Bbuf, W2T, W1TT, bsplit, N, E, G);

    hipLaunchKernelGGL(edge_mlp, dim3(G), dim3(256), 0, stream,
                       (const unsigned short*)Xg, Bbuf, nbr, rs, bsplit,
                       (unsigned short*)Hout, W1TT, N, E, G);

    int stripes = (N + 15) / 16;
    int g3 = (stripes + 3) / 4;
    hipLaunchKernelGGL(h_w2_mfma, dim3(g3), dim3(256), 0, stream,
                       (const unsigned short*)Hout, W2T, b2, rs, outp, N);
}

// Round 9
// 158.763 us; speedup vs baseline: 1.3031x; 1.3031x over previous
//
#include <hip/hip_runtime.h>
#include <hip/hip_bf16.h>
#include <math.h>

#define C_IN  64
#define HID   128
#define C_OUT 64
#define K1_NODES 64

typedef __attribute__((ext_vector_type(8))) short s16x8;   // 8 bf16 (4 VGPR)
typedef __attribute__((ext_vector_type(4))) float f32x4;   // MFMA acc
typedef __attribute__((ext_vector_type(2))) float f32x2;   // packed-fp32 pair

// ---------------------------------------------------------------------------
// Fast GELU (tanh form), PACKED 2-wide. Bit-identical math to prior rounds.
// ---------------------------------------------------------------------------
__device__ __forceinline__ f32x2 gelu2(f32x2 x) {
    f32x2 t  = x * x;                                   // pk_mul
    f32x2 p  = t * 0.10294455f + 2.30211462f;           // pk_fma
    f32x2 xp = x * p;                                   // pk_mul
    f32x2 E;
    E.x = __builtin_amdgcn_exp2f(xp.x);                 // trans
    E.y = __builtin_amdgcn_exp2f(xp.y);                 // trans
    f32x2 Ep = E + 1.0f;                                // pk_add
    f32x2 r;
    r.x = __builtin_amdgcn_rcpf(Ep.x);                  // trans
    r.y = __builtin_amdgcn_rcpf(Ep.y);                  // trans
    return x - x * r;                                   // pk_fma
}

__device__ __forceinline__ float4 fma4(float s, float4 w, float4 acc) {
    acc.x = fmaf(s, w.x, acc.x); acc.y = fmaf(s, w.y, acc.y);
    acc.z = fmaf(s, w.z, acc.z); acc.w = fmaf(s, w.w, acc.w);
    return acc;
}

__device__ __forceinline__ unsigned pk_bf16(float lo, float hi) {
    union { __hip_bfloat162 v; unsigned u; } cv;
    cv.v = __float22bfloat162_rn(make_float2(lo, hi));
    return cv.u;
}
// unpack dword of 2x bf16 -> f32x2 (consecutive VGPRs -> pk-friendly)
__device__ __forceinline__ f32x2 unpk2(unsigned p) {
    union { unsigned u; float f; } lo, hi;
    lo.u = p << 16; hi.u = p & 0xffff0000u;
    f32x2 v; v.x = lo.f; v.y = hi.f; return v;
}

// ---------------------------------------------------------------------------
// Kernel 1: per-node factored first linear ([50000x64] @ [64x256] GEMM).
//   A16[n][h] = bf16( X[n][:] . W1[0:64,h] )       (gathered per-edge)
//   B  [n][h] =       X[n][:] . W1[64:128,h] + b1  (read per-row, f32)
// Block 0 additionally transposes W2 -> W2T[c][k] bf16 for the fused epilogue.
// Also precomputes the edge-balanced block->row partition for edge_agg.
// ---------------------------------------------------------------------------
__global__ __launch_bounds__(512, 2) void precompute_ab(
    const float* __restrict__ X, const float* __restrict__ W1,
    const float* __restrict__ b1, const float* __restrict__ W2,
    const int* __restrict__ rs,
    unsigned* __restrict__ A16, float* __restrict__ B,
    unsigned short* __restrict__ W2T, int* __restrict__ bsplit,
    int N, int E, int G)
{
    __shared__ float W1s[2 * C_IN * HID];     // 64 KiB
    __shared__ float xs[K1_NODES * C_IN];     // 16 KiB
    int tid = threadIdx.x;

    for (int i = tid; i < (2 * C_IN * HID) / 4; i += 512)
        ((float4*)W1s)[i] = ((const float4*)W1)[i];

    int base = blockIdx.x * K1_NODES;
    int nLoc = min(K1_NODES, N - base);
    for (int i = tid; i < nLoc * (C_IN / 4); i += 512)
        ((float4*)xs)[i] = ((const float4*)(X + (size_t)base * C_IN))[i];

    if (blockIdx.x == 0) {                     // one-time W2 -> bf16 k-major
        for (int i = tid; i < C_OUT * HID; i += 512) {
            int c = i >> 7, k = i & (HID - 1);
            W2T[i] = (unsigned short)pk_bf16(W2[k * C_OUT + c], 0.f);
        }
    }

    // ---- block->row partition for edge_agg (lane-parallel binary search) ----
    {
        int gi = blockIdx.x * 512 + tid;
        if (gi <= G) {
            int t = (int)(((long long)E * gi) / G);
            int lo = 0, hi = N;
            while (lo < hi) { int mm = (lo + hi) >> 1; if (rs[mm] < t) lo = mm + 1; else hi = mm; }
            bsplit[gi] = lo;
        }
    }

    __syncthreads();

    int quad = (tid & 31) * 4;    // h-quad 0,4,...,124
    int slot = tid >> 5;          // 0..15, owns nodes 4*slot .. 4*slot+3
    int s0   = slot * 4;
    if (s0 >= nLoc) return;

    float4 a0 = {}, a1 = {}, a2 = {}, a3 = {};
    float4 b0 = {}, b1r = {}, b2r = {}, b3 = {};

    const float* xr0 = xs + (s0 + 0) * C_IN;
    const float* xr1 = xs + (s0 + 1) * C_IN;
    const float* xr2 = xs + (s0 + 2) * C_IN;
    const float* xr3 = xs + (s0 + 3) * C_IN;

#define K1STEP(c, CMP)                                                      \
    do {                                                                    \
        float4 wa = *(const float4*)&W1s[(c) * HID + quad];                 \
        float4 wb = *(const float4*)&W1s[((c) + C_IN) * HID + quad];        \
        a0 = fma4(xv0.CMP, wa, a0); b0  = fma4(xv0.CMP, wb, b0);            \
        a1 = fma4(xv1.CMP, wa, a1); b1r = fma4(xv1.CMP, wb, b1r);           \
        a2 = fma4(xv2.CMP, wa, a2); b2r = fma4(xv2.CMP, wb, b2r);           \
        a3 = fma4(xv3.CMP, wa, a3); b3  = fma4(xv3.CMP, wb, b3);            \
    } while (0)

#pragma unroll 1
    for (int c4 = 0; c4 < C_IN; c4 += 4) {
        float4 xv0 = *(const float4*)&xr0[c4];
        float4 xv1 = *(const float4*)&xr1[c4];
        float4 xv2 = *(const float4*)&xr2[c4];
        float4 xv3 = *(const float4*)&xr3[c4];
        K1STEP(c4 + 0, x);
        K1STEP(c4 + 1, y);
        K1STEP(c4 + 2, z);
        K1STEP(c4 + 3, w);
    }
#undef K1STEP

    float4 bb = *(const float4*)(b1 + quad);
    b0.x += bb.x;  b0.y += bb.y;  b0.z += bb.z;  b0.w += bb.w;
    b1r.x += bb.x; b1r.y += bb.y; b1r.z += bb.z; b1r.w += bb.w;
    b2r.x += bb.x; b2r.y += bb.y; b2r.z += bb.z; b2r.w += bb.w;
    b3.x += bb.x;  b3.y += bb.y;  b3.z += bb.z;  b3.w += bb.w;

    int adw = (base + s0) * (HID / 2) + (quad >> 1);
    size_t boff = (size_t)(base + s0) * HID + quad;
    if (s0 + 0 < nLoc) {
        uint2 u = { pk_bf16(a0.x, a0.y), pk_bf16(a0.z, a0.w) };
        *(uint2*)(A16 + adw) = u;              *(float4*)(B + boff) = b0;
    }
    if (s0 + 1 < nLoc) {
        uint2 u = { pk_bf16(a1.x, a1.y), pk_bf16(a1.z, a1.w) };
        *(uint2*)(A16 + adw + HID / 2) = u;    *(float4*)(B + boff + HID) = b1r;
    }
    if (s0 + 2 < nLoc) {
        uint2 u = { pk_bf16(a2.x, a2.y), pk_bf16(a2.z, a2.w) };
        *(uint2*)(A16 + adw + HID) = u;        *(float4*)(B + boff + 2 * HID) = b2r;
    }
    if (s0 + 3 < nLoc) {
        uint2 u = { pk_bf16(a3.x, a3.y), pk_bf16(a3.z, a3.w) };
        *(uint2*)(A16 + adw + 3 * (HID / 2)) = u; *(float4*)(B + boff + 3 * HID) = b3;
    }
}

// ---------------------------------------------------------------------------
// Kernel 2 (FUSED): R2's edge aggregation + in-block W2 MFMA epilogue.
//   * Edge loop is R2's (2 waves, dwordx2 gathers, 3-buffer 2-ahead pipeline,
//     cross-row prefetch) bounded to 16-row tiles.
//   * H rows (same bf16 bits Hout had) go to LDS; after a barrier both waves
//     run the exact h_w2_mfma fragment pattern (wave w -> cols [32w,32w+32))
//     and store `out` directly. Saves the K3 launch + Hout round-trip.
// ---------------------------------------------------------------------------
#define EA_WAVES 2
#define HS_STR 136   // LDS row stride in shorts (128 + 8 pad)

#define EA_ISSUE(P0,P1,P2,P3, g) do { int _s8 = ((g) << 3) + half;            \
    int _i0 = __shfl(idx, _s8);                                               \
    int _i1 = __shfl(idx, _s8 + 2);                                           \
    int _i2 = __shfl(idx, _s8 + 4);                                           \
    int _i3 = __shfl(idx, _s8 + 6);                                           \
    P0 = *(const uint2*)(A8 + ((((unsigned)_i0) << 8) | lb));                 \
    P1 = *(const uint2*)(A8 + ((((unsigned)_i1) << 8) | lb));                 \
    P2 = *(const uint2*)(A8 + ((((unsigned)_i2) << 8) | lb));                 \
    P3 = *(const uint2*)(A8 + ((((unsigned)_i3) << 8) | lb));                 \
} while (0)

#define EA_PROC1(P) do {                                                      \
    acc01 += gelu2(unpk2(P.x) + bb01);                                        \
    acc23 += gelu2(unpk2(P.y) + bb23); } while (0)

#define EA_PROC1M(P, p) do {                                                  \
    float _mk = ((((p) << 1) + half) < m) ? 1.f : 0.f;                        \
    acc01 += gelu2(unpk2(P.x) + bb01) * _mk;                                  \
    acc23 += gelu2(unpk2(P.y) + bb23) * _mk; } while (0)

#define EA_PROCG(P0,P1,P2,P3, g) do {                                         \
    if ((((g) + 1) << 3) <= m) { EA_PROC1(P0); EA_PROC1(P1);                  \
                                 EA_PROC1(P2); EA_PROC1(P3); }                \
    else { int _p = (g) << 2;                                                 \
           EA_PROC1M(P0, _p);                                                 \
           if (((_p + 1) << 1) < m) EA_PROC1M(P1, _p + 1);                    \
           if (((_p + 2) << 1) < m) EA_PROC1M(P2, _p + 2);                    \
           if (((_p + 3) << 1) < m) EA_PROC1M(P3, _p + 3); } } while (0)

__global__ __launch_bounds__(128) void edge_agg_fused(
    const unsigned* __restrict__ A16, const float* __restrict__ B,
    const int* __restrict__ nbr, const int* __restrict__ rs,
    const int* __restrict__ bsplit, const unsigned short* __restrict__ W2T,
    const float* __restrict__ b2, float* __restrict__ out,
    int N, int E, int G)
{
    __shared__ unsigned short Hs[16 * HS_STR];   // 4.25 KiB

    int wave = threadIdx.x >> 6, lane = threadIdx.x & 63;
    int half = lane >> 5, l5 = lane & 31;
    int r16 = lane & 15, kg = lane >> 4;
    const char* A8 = (const char*)A16;
    unsigned lb = (unsigned)(l5 << 3);          // byte offset within row
    int b = blockIdx.x;

    int r0 = bsplit[b];
    int r1 = (b == G - 1) ? N : bsplit[b + 1];

    for (int tb = r0; tb < r1; tb += 16) {
        int te = min(tb + 16, r1);

        // ============== edge phase (R2 loop, bounded to [tb,te)) ===========
        int row = tb + wave;
        if (row < te) {
            int s = rs[row], e = rs[row + 1];
            float4 bb4 = *(const float4*)(B + (size_t)row * HID + l5 * 4);
            int idx = 0;
            if (e > s) { int mn = min(64, e - s); idx = nbr[s + min(lane, mn - 1)]; }

            for (;;) {
                int cnt = e - s;

                int nrow = row + EA_WAVES;
                bool hasn = nrow < te;
                int sn = s, en = e;
                float4 bbn = bb4;
                if (hasn) {
                    sn = rs[nrow]; en = rs[nrow + 1];
                    bbn = *(const float4*)(B + (size_t)nrow * HID + l5 * 4);
                }

                f32x2 bb01, bb23;
                bb01.x = bb4.x; bb01.y = bb4.y; bb23.x = bb4.z; bb23.y = bb4.w;
                f32x2 acc01 = {0.f, 0.f}, acc23 = {0.f, 0.f};

                if (cnt > 0) {
                    int cs = s;
                    for (;;) {                      // chunk loop (64 edges)
                        int m = min(64, e - cs);
                        int ng = (m + 7) >> 3;

                        uint2 A0, A1, A2, A3, B0, B1, B2, B3, C0, C1, C2, C3;
                        EA_ISSUE(A0, A1, A2, A3, 0);
                        if (ng > 1) EA_ISSUE(B0, B1, B2, B3, 1);

                        int ncs = cs + 64;
                        int idx_next = idx;
                        if (ncs < e) {
                            int mn = min(64, e - ncs);
                            idx_next = nbr[ncs + min(lane, mn - 1)];
                        } else if (hasn && en > sn) {
                            int mn = min(64, en - sn);
                            idx_next = nbr[sn + min(lane, mn - 1)];
                        }

                        int g = 0;
                        for (;;) {                  // 3-stage rotation, 2 ahead
                            if (g + 2 < ng) EA_ISSUE(C0, C1, C2, C3, g + 2);
                            EA_PROCG(A0, A1, A2, A3, g);
                            if (++g >= ng) break;
                            if (g + 2 < ng) EA_ISSUE(A0, A1, A2, A3, g + 2);
                            EA_PROCG(B0, B1, B2, B3, g);
                            if (++g >= ng) break;
                            if (g + 2 < ng) EA_ISSUE(B0, B1, B2, B3, g + 2);
                            EA_PROCG(C0, C1, C2, C3, g);
                            if (++g >= ng) break;
                        }

                        idx = idx_next;
                        if (ncs >= e) break;
                        cs = ncs;
                    }
                } else if (hasn && en > sn) {       // empty row: keep idx alive
                    int mn = min(64, en - sn);
                    idx = nbr[sn + min(lane, mn - 1)];
                }

                acc01.x += __shfl_xor(acc01.x, 32);
                acc01.y += __shfl_xor(acc01.y, 32);
                acc23.x += __shfl_xor(acc23.x, 32);
                acc23.y += __shfl_xor(acc23.y, 32);

                if (half == 0) {                    // H row -> LDS (bf16 bits)
                    float sc = (cnt > 0) ? 1.f / (float)cnt : 0.f;
                    uint2 o = { pk_bf16(acc01.x * sc, acc01.y * sc),
                                pk_bf16(acc23.x * sc, acc23.y * sc) };
                    *(uint2*)(&Hs[(row - tb) * HS_STR + l5 * 4]) = o;
                }

                if (!hasn) break;
                row = nrow; s = sn; e = en; bb4 = bbn;
            }
        }
        __syncthreads();

        // ============== MFMA epilogue (h_w2_mfma pattern) ==================
        {
            const unsigned short* hrow = Hs + r16 * HS_STR + kg * 8;
            int c0 = wave * 32;                       // wave w -> cols [32w,32w+32)
            const unsigned short* wcA = W2T + (size_t)(c0 + r16) * HID + kg * 8;
            const unsigned short* wcB = W2T + (size_t)(c0 + 16 + r16) * HID + kg * 8;

            f32x4 accA = {0.f, 0.f, 0.f, 0.f};
            f32x4 accB = accA;
#pragma unroll
            for (int kk = 0; kk < 4; ++kk) {
                s16x8 a  = *(const s16x8*)(hrow + kk * 32);
                s16x8 fA = *(const s16x8*)(wcA + kk * 32);
                s16x8 fB = *(const s16x8*)(wcB + kk * 32);
                accA = __builtin_amdgcn_mfma_f32_16x16x32_bf16(a, fA, accA, 0, 0, 0);
                accB = __builtin_amdgcn_mfma_f32_16x16x32_bf16(a, fB, accB, 0, 0, 0);
            }

            float biaA = b2[c0 + r16];
            float biaB = b2[c0 + 16 + r16];
#pragma unroll
            for (int r = 0; r < 4; ++r) {
                int rowi = tb + kg * 4 + r;
                if (rowi < te) {
                    float mmk = (rs[rowi + 1] > rs[rowi]) ? 1.f : 0.f;
                    float* o = out + (size_t)rowi * C_OUT;
                    o[c0 + r16]      = mmk * (accA[r] + biaA);
                    o[c0 + 16 + r16] = mmk * (accB[r] + biaB);
                }
            }
        }
        __syncthreads();   // Hs reused by next tile
    }
}

#undef EA_ISSUE
#undef EA_PROC1
#undef EA_PROC1M
#undef EA_PROCG

// ---------------------------------------------------------------------------
extern "C" void kernel_launch(void* const* d_in, const int* in_sizes, int n_in,
                              void* d_out, int out_size, void* d_ws, size_t ws_size,
                              hipStream_t stream) {
    const float* X  = (const float*)d_in[0];
    const float* W1 = (const float*)d_in[1];
    const float* b1 = (const float*)d_in[2];
    const float* W2 = (const float*)d_in[3];
    const float* b2 = (const float*)d_in[4];
    const int*   nbr = (const int*)d_in[5];
    const int*   rs  = (const int*)d_in[6];
    float* outp = (float*)d_out;

    int N = in_sizes[6] - 1;                  // row_splits has N+1 entries
    int E = in_sizes[5];                      // total edges

    int G = 12288;

    // workspace layout (~38.5 MB):
    unsigned*       A16  = (unsigned*)d_ws;                          // N*64 dw
    float*          Bbuf = (float*)(A16 + (size_t)N * (HID / 2));    // N*128 f32
    unsigned short* W2T  = (unsigned short*)(Bbuf + (size_t)N * HID); // 8192 shorts
    int*            bsplit = (int*)(W2T + C_OUT * HID);              // G+1 ints

    int g1 = (N + K1_NODES - 1) / K1_NODES;
    hipLaunchKernelGGL(precompute_ab, dim3(g1), dim3(512), 0, stream,
                       X, W1, b1, W2, rs, A16, Bbuf, W2T, bsplit, N, E, G);

    hipLaunchKernelGGL(edge_agg_fused, dim3(G), dim3(128), 0, stream,
                       A16, Bbuf, nbr, rs, bsplit, W2T, b2, outp, N, E, G);
}

// Round 10
// 132.359 us; speedup vs baseline: 1.5631x; 1.1995x over previous
//
#include <hip/hip_runtime.h>
#include <hip/hip_bf16.h>
#include <math.h>

#define C_IN  64
#define HID   128
#define C_OUT 64

typedef __attribute__((ext_vector_type(8))) short s16x8;   // 8 bf16 (4 VGPR)
typedef __attribute__((ext_vector_type(4))) float f32x4;   // MFMA acc
typedef __attribute__((ext_vector_type(2))) float f32x2;   // packed-fp32 pair

// ---------------------------------------------------------------------------
// Fast GELU (tanh form), PACKED 2-wide. Bit-identical math to prior rounds.
// ---------------------------------------------------------------------------
__device__ __forceinline__ f32x2 gelu2(f32x2 x) {
    f32x2 t  = x * x;                                   // pk_mul
    f32x2 p  = t * 0.10294455f + 2.30211462f;           // pk_fma
    f32x2 xp = x * p;                                   // pk_mul
    f32x2 E;
    E.x = __builtin_amdgcn_exp2f(xp.x);                 // trans
    E.y = __builtin_amdgcn_exp2f(xp.y);                 // trans
    f32x2 Ep = E + 1.0f;                                // pk_add
    f32x2 r;
    r.x = __builtin_amdgcn_rcpf(Ep.x);                  // trans
    r.y = __builtin_amdgcn_rcpf(Ep.y);                  // trans
    return x - x * r;                                   // pk_fma
}

__device__ __forceinline__ float4 fma4(float s, float4 w, float4 acc) {
    acc.x = fmaf(s, w.x, acc.x); acc.y = fmaf(s, w.y, acc.y);
    acc.z = fmaf(s, w.z, acc.z); acc.w = fmaf(s, w.w, acc.w);
    return acc;
}

__device__ __forceinline__ unsigned pk_bf16(float lo, float hi) {
    union { __hip_bfloat162 v; unsigned u; } cv;
    cv.v = __float22bfloat162_rn(make_float2(lo, hi));
    return cv.u;
}
// unpack dword of 2x bf16 -> f32x2 (consecutive VGPRs -> pk-friendly)
__device__ __forceinline__ f32x2 unpk2(unsigned p) {
    union { unsigned u; float f; } lo, hi;
    lo.u = p << 16; hi.u = p & 0xffff0000u;
    f32x2 v; v.x = lo.f; v.y = hi.f; return v;
}

// ---------------------------------------------------------------------------
// Kernel 1: per-node factored first linear ([50000x64] @ [64x256] GEMM).
//   A16[n][h] = bf16( X[n][:] . W1[0:64,h] )       (gathered per-edge)
//   B  [n][h] =       X[n][:] . W1[64:128,h] + b1  (read per-row, f32)
// Block 0 additionally transposes W2 -> W2T[c][k] bf16 for the MFMA kernel.
// Also precomputes the edge-balanced block->row partition for edge_agg.
// ---------------------------------------------------------------------------
#define K1_NODES 64

__global__ __launch_bounds__(512, 2) void precompute_ab(
    const float* __restrict__ X, const float* __restrict__ W1,
    const float* __restrict__ b1, const float* __restrict__ W2,
    const int* __restrict__ rs,
    unsigned* __restrict__ A16, float* __restrict__ B,
    unsigned short* __restrict__ W2T, int* __restrict__ bsplit,
    int N, int E, int G)
{
    __shared__ float W1s[2 * C_IN * HID];     // 64 KiB
    __shared__ float xs[K1_NODES * C_IN];     // 16 KiB
    int tid = threadIdx.x;

    for (int i = tid; i < (2 * C_IN * HID) / 4; i += 512)
        ((float4*)W1s)[i] = ((const float4*)W1)[i];

    int base = blockIdx.x * K1_NODES;
    int nLoc = min(K1_NODES, N - base);
    for (int i = tid; i < nLoc * (C_IN / 4); i += 512)
        ((float4*)xs)[i] = ((const float4*)(X + (size_t)base * C_IN))[i];

    if (blockIdx.x == 0) {                     // one-time W2 -> bf16 k-major
        for (int i = tid; i < C_OUT * HID; i += 512) {
            int c = i >> 7, k = i & (HID - 1);
            W2T[i] = (unsigned short)pk_bf16(W2[k * C_OUT + c], 0.f);
        }
    }

    // ---- block->row partition for edge_agg (lane-parallel binary search) ----
    {
        int gi = blockIdx.x * 512 + tid;
        if (gi <= G) {
            int t = (int)(((long long)E * gi) / G);
            int lo = 0, hi = N;
            while (lo < hi) { int mm = (lo + hi) >> 1; if (rs[mm] < t) lo = mm + 1; else hi = mm; }
            bsplit[gi] = lo;
        }
    }

    __syncthreads();

    int quad = (tid & 31) * 4;    // h-quad 0,4,...,124
    int slot = tid >> 5;          // 0..15, owns nodes 4*slot .. 4*slot+3
    int s0   = slot * 4;
    if (s0 >= nLoc) return;

    float4 a0 = {}, a1 = {}, a2 = {}, a3 = {};
    float4 b0 = {}, b1r = {}, b2r = {}, b3 = {};

    const float* xr0 = xs + (s0 + 0) * C_IN;
    const float* xr1 = xs + (s0 + 1) * C_IN;
    const float* xr2 = xs + (s0 + 2) * C_IN;
    const float* xr3 = xs + (s0 + 3) * C_IN;

#define K1STEP(c, CMP)                                                      \
    do {                                                                    \
        float4 wa = *(const float4*)&W1s[(c) * HID + quad];                 \
        float4 wb = *(const float4*)&W1s[((c) + C_IN) * HID + quad];        \
        a0 = fma4(xv0.CMP, wa, a0); b0  = fma4(xv0.CMP, wb, b0);            \
        a1 = fma4(xv1.CMP, wa, a1); b1r = fma4(xv1.CMP, wb, b1r);           \
        a2 = fma4(xv2.CMP, wa, a2); b2r = fma4(xv2.CMP, wb, b2r);           \
        a3 = fma4(xv3.CMP, wa, a3); b3  = fma4(xv3.CMP, wb, b3);            \
    } while (0)

#pragma unroll 1
    for (int c4 = 0; c4 < C_IN; c4 += 4) {
        float4 xv0 = *(const float4*)&xr0[c4];
        float4 xv1 = *(const float4*)&xr1[c4];
        float4 xv2 = *(const float4*)&xr2[c4];
        float4 xv3 = *(const float4*)&xr3[c4];
        K1STEP(c4 + 0, x);
        K1STEP(c4 + 1, y);
        K1STEP(c4 + 2, z);
        K1STEP(c4 + 3, w);
    }
#undef K1STEP

    float4 bb = *(const float4*)(b1 + quad);
    b0.x += bb.x;  b0.y += bb.y;  b0.z += bb.z;  b0.w += bb.w;
    b1r.x += bb.x; b1r.y += bb.y; b1r.z += bb.z; b1r.w += bb.w;
    b2r.x += bb.x; b2r.y += bb.y; b2r.z += bb.z; b2r.w += bb.w;
    b3.x += bb.x;  b3.y += bb.y;  b3.z += bb.z;  b3.w += bb.w;

    int adw = (base + s0) * (HID / 2) + (quad >> 1);
    size_t boff = (size_t)(base + s0) * HID + quad;
    if (s0 + 0 < nLoc) {
        uint2 u = { pk_bf16(a0.x, a0.y), pk_bf16(a0.z, a0.w) };
        *(uint2*)(A16 + adw) = u;              *(float4*)(B + boff) = b0;
    }
    if (s0 + 1 < nLoc) {
        uint2 u = { pk_bf16(a1.x, a1.y), pk_bf16(a1.z, a1.w) };
        *(uint2*)(A16 + adw + HID / 2) = u;    *(float4*)(B + boff + HID) = b1r;
    }
    if (s0 + 2 < nLoc) {
        uint2 u = { pk_bf16(a2.x, a2.y), pk_bf16(a2.z, a2.w) };
        *(uint2*)(A16 + adw + HID) = u;        *(float4*)(B + boff + 2 * HID) = b2r;
    }
    if (s0 + 3 < nLoc) {
        uint2 u = { pk_bf16(a3.x, a3.y), pk_bf16(a3.z, a3.w) };
        *(uint2*)(A16 + adw + 3 * (HID / 2)) = u; *(float4*)(B + boff + 3 * HID) = b3;
    }
}

// ---------------------------------------------------------------------------
// Kernel 2: latency-hiding edge aggregation — R2 structure (the measured
// best), with G halved to 6144 so each wave owns ~4 rows: the per-block
// cold-start chain (bsplit->rs->B/nbr->gather) is paid half as often and
// the cross-row prefetch covers 3 row transitions instead of 1.
//   * 2 edges per gather instruction (32 lanes/edge, dwordx2/lane).
//   * block row-range from precomputed bsplit (no binary search).
//   * cross-row + cross-chunk idx prefetch; gathers 2 groups (16 edges)
//     ahead via 3 static buffers.
// ---------------------------------------------------------------------------
#define EA_WAVES 2

#define EA_ISSUE(P0,P1,P2,P3, g) do { int _s8 = ((g) << 3) + half;            \
    int _i0 = __shfl(idx, _s8);                                               \
    int _i1 = __shfl(idx, _s8 + 2);                                           \
    int _i2 = __shfl(idx, _s8 + 4);                                           \
    int _i3 = __shfl(idx, _s8 + 6);                                           \
    P0 = *(const uint2*)(A8 + ((((unsigned)_i0) << 8) | lb));                 \
    P1 = *(const uint2*)(A8 + ((((unsigned)_i1) << 8) | lb));                 \
    P2 = *(const uint2*)(A8 + ((((unsigned)_i2) << 8) | lb));                 \
    P3 = *(const uint2*)(A8 + ((((unsigned)_i3) << 8) | lb));                 \
} while (0)

#define EA_PROC1(P) do {                                                      \
    acc01 += gelu2(unpk2(P.x) + bb01);                                        \
    acc23 += gelu2(unpk2(P.y) + bb23); } while (0)

#define EA_PROC1M(P, p) do {                                                  \
    float _mk = ((((p) << 1) + half) < m) ? 1.f : 0.f;                        \
    acc01 += gelu2(unpk2(P.x) + bb01) * _mk;                                  \
    acc23 += gelu2(unpk2(P.y) + bb23) * _mk; } while (0)

#define EA_PROCG(P0,P1,P2,P3, g) do {                                         \
    if ((((g) + 1) << 3) <= m) { EA_PROC1(P0); EA_PROC1(P1);                  \
                                 EA_PROC1(P2); EA_PROC1(P3); }                \
    else { int _p = (g) << 2;                                                 \
           EA_PROC1M(P0, _p);                                                 \
           if (((_p + 1) << 1) < m) EA_PROC1M(P1, _p + 1);                    \
           if (((_p + 2) << 1) < m) EA_PROC1M(P2, _p + 2);                    \
           if (((_p + 3) << 1) < m) EA_PROC1M(P3, _p + 3); } } while (0)

__global__ __launch_bounds__(128) void edge_agg(
    const unsigned* __restrict__ A16, const float* __restrict__ B,
    const int* __restrict__ nbr, const int* __restrict__ rs,
    const int* __restrict__ bsplit,
    unsigned* __restrict__ Hout, int N, int E, int G)
{
    int wave = threadIdx.x >> 6, lane = threadIdx.x & 63;
    int half = lane >> 5, l5 = lane & 31;
    const char* A8 = (const char*)A16;
    unsigned lb = (unsigned)(l5 << 3);          // byte offset within row
    int b = blockIdx.x;

    int r0 = bsplit[b];
    int r1 = (b == G - 1) ? N : bsplit[b + 1];

    int row = r0 + wave;
    if (row >= r1) return;

    // prologue: current row meta + first index chunk
    int s = rs[row], e = rs[row + 1];
    float4 bb4 = *(const float4*)(B + (size_t)row * HID + l5 * 4);
    int idx = 0;
    if (e > s) { int mn = min(64, e - s); idx = nbr[s + min(lane, mn - 1)]; }

    for (;;) {
        int cnt = e - s;

        // prefetch next row's meta early (lands under this row's compute)
        int nrow = row + EA_WAVES;
        bool hasn = nrow < r1;
        int sn = s, en = e;
        float4 bbn = bb4;
        if (hasn) {
            sn = rs[nrow]; en = rs[nrow + 1];
            bbn = *(const float4*)(B + (size_t)nrow * HID + l5 * 4);
        }

        f32x2 bb01, bb23;
        bb01.x = bb4.x; bb01.y = bb4.y; bb23.x = bb4.z; bb23.y = bb4.w;
        f32x2 acc01 = {0.f, 0.f}, acc23 = {0.f, 0.f};

        if (cnt > 0) {
            int cs = s;
            for (;;) {                          // chunk loop (64 edges/chunk)
                int m = min(64, e - cs);
                int ng = (m + 7) >> 3;

                uint2 A0, A1, A2, A3, B0, B1, B2, B3, C0, C1, C2, C3;
                EA_ISSUE(A0, A1, A2, A3, 0);
                if (ng > 1) EA_ISSUE(B0, B1, B2, B3, 1);

                // prefetch next index chunk (same row) or next row's chunk 0
                int ncs = cs + 64;
                int idx_next = idx;
                if (ncs < e) {
                    int mn = min(64, e - ncs);
                    idx_next = nbr[ncs + min(lane, mn - 1)];
                } else if (hasn && en > sn) {
                    int mn = min(64, en - sn);
                    idx_next = nbr[sn + min(lane, mn - 1)];
                }

                int g = 0;
                for (;;) {                      // 3-stage rotation, 2 groups ahead
                    if (g + 2 < ng) EA_ISSUE(C0, C1, C2, C3, g + 2);
                    EA_PROCG(A0, A1, A2, A3, g);
                    if (++g >= ng) break;
                    if (g + 2 < ng) EA_ISSUE(A0, A1, A2, A3, g + 2);
                    EA_PROCG(B0, B1, B2, B3, g);
                    if (++g >= ng) break;
                    if (g + 2 < ng) EA_ISSUE(B0, B1, B2, B3, g + 2);
                    EA_PROCG(C0, C1, C2, C3, g);
                    if (++g >= ng) break;
                }

                idx = idx_next;
                if (ncs >= e) break;
                cs = ncs;
            }
        } else if (hasn && en > sn) {           // empty row: keep idx chain alive
            int mn = min(64, en - sn);
            idx = nbr[sn + min(lane, mn - 1)];
        }

        // merge the two half-wave edge partial sums
        acc01.x += __shfl_xor(acc01.x, 32);
        acc01.y += __shfl_xor(acc01.y, 32);
        acc23.x += __shfl_xor(acc23.x, 32);
        acc23.y += __shfl_xor(acc23.y, 32);

        if (half == 0) {
            float sc = (cnt > 0) ? 1.f / (float)cnt : 0.f;
            uint2 o = { pk_bf16(acc01.x * sc, acc01.y * sc),
                        pk_bf16(acc23.x * sc, acc23.y * sc) };
            ((uint2*)(Hout + (size_t)row * (HID / 2)))[l5] = o;
        }

        if (!hasn) break;
        row = nrow; s = sn; e = en; bb4 = bbn;
    }
}

#undef EA_ISSUE
#undef EA_PROC1
#undef EA_PROC1M
#undef EA_PROCG

// ---------------------------------------------------------------------------
// Kernel 3: out = Hbar @ W2 + b2 via MFMA (bf16 in, f32 out). Unchanged.
// ---------------------------------------------------------------------------
__global__ __launch_bounds__(256) void h_w2_mfma(
    const unsigned short* __restrict__ H, const unsigned short* __restrict__ W2T,
    const float* __restrict__ b2, const int* __restrict__ rs,
    float* __restrict__ out, int N)
{
    int wave = threadIdx.x >> 6, lane = threadIdx.x & 63;
    int base = (blockIdx.x * 4 + wave) * 16;
    if (base >= N) return;

    int r16 = lane & 15;
    int kg  = lane >> 4;

    const unsigned short* hrow = H + (size_t)(base + r16) * HID + kg * 8;
    const unsigned short* wc0  = W2T + (size_t)(0 * 16 + r16) * HID + kg * 8;
    const unsigned short* wc1  = W2T + (size_t)(1 * 16 + r16) * HID + kg * 8;
    const unsigned short* wc2  = W2T + (size_t)(2 * 16 + r16) * HID + kg * 8;
    const unsigned short* wc3  = W2T + (size_t)(3 * 16 + r16) * HID + kg * 8;

    f32x4 acc0 = {0.f, 0.f, 0.f, 0.f};
    f32x4 acc1 = acc0, acc2 = acc0, acc3 = acc0;

#pragma unroll
    for (int kk = 0; kk < 4; ++kk) {
        s16x8 a  = *(const s16x8*)(hrow + kk * 32);
        s16x8 f0 = *(const s16x8*)(wc0 + kk * 32);
        s16x8 f1 = *(const s16x8*)(wc1 + kk * 32);
        s16x8 f2 = *(const s16x8*)(wc2 + kk * 32);
        s16x8 f3 = *(const s16x8*)(wc3 + kk * 32);
        acc0 = __builtin_amdgcn_mfma_f32_16x16x32_bf16(a, f0, acc0, 0, 0, 0);
        acc1 = __builtin_amdgcn_mfma_f32_16x16x32_bf16(a, f1, acc1, 0, 0, 0);
        acc2 = __builtin_amdgcn_mfma_f32_16x16x32_bf16(a, f2, acc2, 0, 0, 0);
        acc3 = __builtin_amdgcn_mfma_f32_16x16x32_bf16(a, f3, acc3, 0, 0, 0);
    }

    float bia0 = b2[r16], bia1 = b2[16 + r16], bia2 = b2[32 + r16], bia3 = b2[48 + r16];

#pragma unroll
    for (int r = 0; r < 4; ++r) {
        int rowi = base + kg * 4 + r;
        if (rowi < N) {
            float mmk = (rs[rowi + 1] > rs[rowi]) ? 1.f : 0.f;
            float* o = out + (size_t)rowi * C_OUT;
            o[r16]      = mmk * (acc0[r] + bia0);
            o[16 + r16] = mmk * (acc1[r] + bia1);
            o[32 + r16] = mmk * (acc2[r] + bia2);
            o[48 + r16] = mmk * (acc3[r] + bia3);
        }
    }
}

// ---------------------------------------------------------------------------
extern "C" void kernel_launch(void* const* d_in, const int* in_sizes, int n_in,
                              void* d_out, int out_size, void* d_ws, size_t ws_size,
                              hipStream_t stream) {
    const float* X  = (const float*)d_in[0];
    const float* W1 = (const float*)d_in[1];
    const float* b1 = (const float*)d_in[2];
    const float* W2 = (const float*)d_in[3];
    const float* b2 = (const float*)d_in[4];
    const int*   nbr = (const int*)d_in[5];
    const int*   rs  = (const int*)d_in[6];
    float* outp = (float*)d_out;

    int N = in_sizes[6] - 1;                  // row_splits has N+1 entries
    int E = in_sizes[5];                      // total edges

    int G = 6144;                             // ~8 rows/block, ~260 edges/block

    // workspace layout (~51.3 MB):
    unsigned*       A16  = (unsigned*)d_ws;                          // N*64 dw
    float*          Bbuf = (float*)(A16 + (size_t)N * (HID / 2));    // N*128 f32
    unsigned*       Hout = (unsigned*)(Bbuf + (size_t)N * HID);      // N*64 dw
    unsigned short* W2T  = (unsigned short*)(Hout + (size_t)N * (HID / 2)); // 8192
    int*            bsplit = (int*)(W2T + C_OUT * HID);              // G+1 ints

    int g1 = (N + K1_NODES - 1) / K1_NODES;
    hipLaunchKernelGGL(precompute_ab, dim3(g1), dim3(512), 0, stream,
                       X, W1, b1, W2, rs, A16, Bbuf, W2T, bsplit, N, E, G);

    hipLaunchKernelGGL(edge_agg, dim3(G), dim3(128), 0, stream,
                       A16, Bbuf, nbr, rs, bsplit, Hout, N, E, G);

    int stripes = (N + 15) / 16;
    int g3 = (stripes + 3) / 4;
    hipLaunchKernelGGL(h_w2_mfma, dim3(g3), dim3(256), 0, stream,
                       (const unsigned short*)Hout, W2T, b2, rs, outp, N);
}